// Round 12
// baseline (511.421 us; speedup 1.0000x reference)
//
#include <hip/hip_runtime.h>

#define DD 64      // input feature dim
#define D2 128     // h1 dim
#define CC 4       // communities / clusters
#define SS 8       // members per community
#define MM 16      // neighbors
#define OUTW 384   // output row width (h1 | h1 | cluster)
#define LDST 132   // padded LDS row stride in floats (16B-aligned float4 reads)

// OpenBLAS small-matrix NT sgemm kernel model (AVX512, one 16-lane acc):
// per lane L: v = fma chain over ascending k-blocks a[16k+L]*b[16k+L]
// (k = 0..7; n = 128 = 8*16 exactly), then _mm512_reduce_add_ps halves-tree
// (lane partner strides 8, 4, 2, 1).
__device__ __forceinline__ float np_dot128_w16fma(const float* __restrict__ a,
                                                  const float* __restrict__ b) {
  #pragma clang fp contract(off)
  float S[16];
  #pragma unroll
  for (int L = 0; L < 16; ++L) {
    float v = 0.f;
    #pragma unroll
    for (int k = 0; k < 8; ++k)
      v = fmaf(a[k * 16 + L], b[k * 16 + L], v);   // chained FMA, ascending k
    S[L] = v;
  }
  float A0 = S[0] + S[8],  A1 = S[1] + S[9],  A2 = S[2] + S[10], A3 = S[3] + S[11];
  float A4 = S[4] + S[12], A5 = S[5] + S[13], A6 = S[6] + S[14], A7 = S[7] + S[15];
  float B0 = A0 + A4, B1 = A1 + A5, B2 = A2 + A6, B3 = A3 + A7;
  float C0 = B0 + B2, C1 = B1 + B3;
  return C0 + C1;
}

// np.sum(ctr*ctr, -1): npyv W16 pairwise (8 vector accs = the 8 loads,
// vector tree-of-8, halves-tree reduce). c^2 micro-order proven inert
// (r8=r9=r10), kept for self-consistency with the AVX512 host model.
__device__ __forceinline__ float np_sumsq128_w16(const float* __restrict__ a) {
  #pragma clang fp contract(off)
  float S[16];
  #pragma unroll
  for (int L = 0; L < 16; ++L) {
    float q0 = a[0*16+L] * a[0*16+L];
    float q1 = a[1*16+L] * a[1*16+L];
    float q2 = a[2*16+L] * a[2*16+L];
    float q3 = a[3*16+L] * a[3*16+L];
    float q4 = a[4*16+L] * a[4*16+L];
    float q5 = a[5*16+L] * a[5*16+L];
    float q6 = a[6*16+L] * a[6*16+L];
    float q7 = a[7*16+L] * a[7*16+L];
    S[L] = ((q0 + q1) + (q2 + q3)) + ((q4 + q5) + (q6 + q7));
  }
  float A0 = S[0] + S[8],  A1 = S[1] + S[9],  A2 = S[2] + S[10], A3 = S[3] + S[11];
  float A4 = S[4] + S[12], A5 = S[5] + S[13], A6 = S[6] + S[14], A7 = S[7] + S[15];
  float B0 = A0 + A4, B1 = A1 + A5, B2 = A2 + A6, B3 = A3 + A7;
  float C0 = B0 + B2, C1 = B1 + B3;
  return C0 + C1;
}

// ---------------- Layer 1: h1 = relu([x, max_c mean_s feat[comm]]) ----------
// one wave per node; lane l owns feature dim l. Mean over members (strided
// reduce, non-last axis) = strictly sequential ascending-s f32 adds, *0.125f.
__global__ __launch_bounds__(256) void sdgnn_k1(
    const float* __restrict__ feat, const int* __restrict__ comm,
    float* __restrict__ out, int N) {
  #pragma clang fp contract(off)
  int wid = (int)((blockIdx.x * blockDim.x + threadIdx.x) >> 6);
  int lane = threadIdx.x & 63;
  if (wid >= N) return;
  const int n = wid;
  int cidx = comm[(size_t)n * (CC * SS) + (lane & 31)];
  float x = feat[(size_t)n * DD + lane];
  float g = 0.f;
  #pragma unroll
  for (int c = 0; c < CC; ++c) {
    float a = 0.f;
    #pragma unroll
    for (int s = 0; s < SS; ++s) {
      int j = __shfl(cidx, c * SS + s);
      a = a + feat[(size_t)j * DD + lane];   // sequential, ascending s
    }
    a = a * 0.125f;                          // /8 exact
    g = (c == 0) ? a : fmaxf(g, a);          // max over c, ascending
  }
  float h1a = fmaxf(x, 0.f);
  float h1b = fmaxf(g, 0.f);
  size_t base = (size_t)n * OUTW;
  out[base + lane] = h1a;
  out[base + 64 + lane] = h1b;
  out[base + 128 + lane] = h1a;              // h2 first half == h1 (relu(h1)=h1)
  out[base + 192 + lane] = h1b;
}

// ---------------- Layer 2: 1-step KMeans + scatter-mean + maxpool -----------
// one wave per node; lane owns dims {2l,2l+1} for staging/aggregation;
// lane = (m = lane>>2, c = lane&3) for the 16x4 distance matrix.
__global__ __launch_bounds__(128) void sdgnn_k2(
    const int* __restrict__ comm, const int* __restrict__ neigh,
    float* __restrict__ out, int N) {
  #pragma clang fp contract(off)
  __shared__ __align__(16) float lds[2][(MM + CC) * LDST];
  const int wave = threadIdx.x >> 6;
  const int lane = threadIdx.x & 63;
  int n = blockIdx.x * 2 + wave;
  if (n >= N) n = N - 1;  // keep both waves alive for barriers (N even)
  float* L = lds[wave];

  const int cidx = comm[(size_t)n * (CC * SS) + (lane & 31)];
  const int nidx = neigh[(size_t)n * MM + (lane & 15)];

  // stage neighbor h1 rows to LDS
  #pragma unroll
  for (int m = 0; m < MM; ++m) {
    int j = __shfl(nidx, m);
    float2 v = *(const float2*)(out + (size_t)j * OUTW + 2 * lane);
    *(float2*)(L + m * LDST + 2 * lane) = v;
  }
  // init centers = mean of 8 member h1 rows: sequential ascending-s adds
  float2 ctr[CC];
  #pragma unroll
  for (int c = 0; c < CC; ++c) {
    float ax = 0.f, ay = 0.f;
    #pragma unroll
    for (int s = 0; s < SS; ++s) {
      int j = __shfl(cidx, c * SS + s);
      float2 v = *(const float2*)(out + (size_t)j * OUTW + 2 * lane);
      ax = ax + v.x;
      ay = ay + v.y;
    }
    ctr[c].x = ax * 0.125f;
    ctr[c].y = ay * 0.125f;
    *(float2*)(L + (MM + c) * LDST + 2 * lane) = ctr[c];
  }
  __syncthreads();

  const int mm = lane >> 2, cc = lane & 3;
  const float* nrow = L + mm * LDST;
  const float* crow = L + (MM + cc) * LDST;

  // E-step, "matmul -> OpenBLAS small NT kernel" model:
  //   dot = W16 chained-FMA per lane + halves-tree reduce.
  //   c2  = np.sum(ctr*ctr,-1) W16 pairwise (inert).
  //   d = c2 - 2*dot; argmin over c with first-min tie-break.
  auto assign_lbl = [&]() -> int {
    #pragma clang fp contract(off)
    float c2 = np_sumsq128_w16(crow);
    float dot = np_dot128_w16fma(nrow, crow);
    float bd = c2 - 2.f * dot;   // 2*dot exact; one rounded subtract
    int bc = cc;
    #pragma unroll
    for (int off = 1; off <= 2; off <<= 1) {
      float od = __shfl_xor(bd, off);
      int oc = __shfl_xor(bc, off);
      if (od < bd || (od == bd && oc < bc)) { bd = od; bc = oc; }
    }
    return bc;  // label of neighbor mm on all 4 group lanes
  };

  // scatter-sum by label + counts, ascending m; one-hot products exact ->
  // fmaf == mul+add bitwise (order-robust across transliterations).
  auto aggregate = [&](int bc, float2 acc[CC], float cnt[CC]) {
    #pragma clang fp contract(off)
    #pragma unroll
    for (int c = 0; c < CC; ++c) { acc[c].x = 0.f; acc[c].y = 0.f; cnt[c] = 0.f; }
    #pragma unroll
    for (int m = 0; m < MM; ++m) {
      int lbl = __shfl(bc, m * 4);
      float2 v = *(const float2*)(L + m * LDST + 2 * lane);
      #pragma unroll
      for (int c = 0; c < CC; ++c) {
        float sel = (lbl == c) ? 1.f : 0.f;
        acc[c].x = fmaf(sel, v.x, acc[c].x);
        acc[c].y = fmaf(sel, v.y, acc[c].y);
        cnt[c] = cnt[c] + sel;
      }
    }
  };

  // E-step on init centers, then M-step
  int lbl0 = assign_lbl();
  float2 a0[CC]; float c0[CC];
  aggregate(lbl0, a0, c0);
  float2 ctr1[CC];
  #pragma unroll
  for (int c = 0; c < CC; ++c) {
    float den = fmaxf(c0[c], 1.f);       // maximum(cnt,1.0)
    float mx = a0[c].x / den;            // IEEE f32 divide
    float my = a0[c].y / den;
    ctr1[c].x = (c0[c] > 0.f) ? mx : ctr[c].x;  // where(cnt>0, mean, center)
    ctr1[c].y = (c0[c] > 0.f) ? my : ctr[c].y;
  }
  __syncthreads();  // WAR: all reads of old centers done
  #pragma unroll
  for (int c = 0; c < CC; ++c)
    *(float2*)(L + (MM + c) * LDST + 2 * lane) = ctr1[c];
  __syncthreads();

  // final E-step + scatter-mean (empty -> 0) + maxpool + relu
  int lbl1 = assign_lbl();
  float2 a1[CC]; float c1n[CC];
  aggregate(lbl1, a1, c1n);
  float rx = 0.f, ry = 0.f;
  #pragma unroll
  for (int c = 0; c < CC; ++c) {
    float den = fmaxf(c1n[c], 1.f);
    float gx = a1[c].x / den;            // empty: 0/1 = +0
    float gy = a1[c].y / den;
    rx = (c == 0) ? gx : fmaxf(rx, gx);  // max over c, ascending
    ry = (c == 0) ? gy : fmaxf(ry, gy);
  }
  size_t base = (size_t)n * OUTW + 256 + 2 * lane;
  float2 res;
  res.x = fmaxf(rx, 0.f);
  res.y = fmaxf(ry, 0.f);
  *(float2*)(out + base) = res;
}

extern "C" void kernel_launch(void* const* d_in, const int* in_sizes, int n_in,
                              void* d_out, int out_size, void* d_ws, size_t ws_size,
                              hipStream_t stream) {
  const float* feat = (const float*)d_in[0];
  const int* comm = (const int*)d_in[1];
  const int* neigh = (const int*)d_in[2];
  float* out = (float*)d_out;
  const int N = in_sizes[0] / DD;

  int blocks1 = (N + 3) / 4;   // 4 waves/block, 1 wave per node
  sdgnn_k1<<<blocks1, 256, 0, stream>>>(feat, comm, out, N);
  int blocks2 = (N + 1) / 2;   // 2 waves/block, 1 wave per node
  sdgnn_k2<<<blocks2, 128, 0, stream>>>(comm, neigh, out, N);
}

// Round 13
// 451.265 us; speedup vs baseline: 1.1333x; 1.1333x over previous
//
#include <hip/hip_runtime.h>

#define DD 64      // input feature dim
#define D2 128     // h1 dim
#define CC 4       // communities / clusters
#define SS 8       // members per community
#define MM 16      // neighbors
#define OUTW 384   // output row width (h1 | h1 | cluster)
#define LDST 132   // padded LDS row stride in floats (16B-aligned float4 reads)

// ---------------- Layer 1: h1 = relu([x, max_c mean_s feat[comm]]) ----------
// one wave per node; lane l owns feature dim l. Mean over members (strided
// reduce, non-last axis) = strictly sequential ascending-s f32 adds, *0.125f.
__global__ __launch_bounds__(256) void sdgnn_k1(
    const float* __restrict__ feat, const int* __restrict__ comm,
    float* __restrict__ out, int N) {
  #pragma clang fp contract(off)
  int wid = (int)((blockIdx.x * blockDim.x + threadIdx.x) >> 6);
  int lane = threadIdx.x & 63;
  if (wid >= N) return;
  const int n = wid;
  int cidx = comm[(size_t)n * (CC * SS) + (lane & 31)];
  float x = feat[(size_t)n * DD + lane];
  float g = 0.f;
  #pragma unroll
  for (int c = 0; c < CC; ++c) {
    float a = 0.f;
    #pragma unroll
    for (int s = 0; s < SS; ++s) {
      int j = __shfl(cidx, c * SS + s);
      a = a + feat[(size_t)j * DD + lane];   // sequential, ascending s
    }
    a = a * 0.125f;                          // /8 exact
    g = (c == 0) ? a : fmaxf(g, a);          // max over c, ascending
  }
  float h1a = fmaxf(x, 0.f);
  float h1b = fmaxf(g, 0.f);
  size_t base = (size_t)n * OUTW;
  out[base + lane] = h1a;
  out[base + 64 + lane] = h1b;
  out[base + 128 + lane] = h1a;              // h2 first half == h1 (relu(h1)=h1)
  out[base + 192 + lane] = h1b;
}

// ---------------- Layer 2: 1-step KMeans + scatter-mean + maxpool -----------
// ONE WAVE PER BLOCK (64 threads) -> LDS 10.5 KiB/block, ~15 blocks/CU
// occupancy, __syncthreads intra-wave cheap. lane owns dims {2l,2l+1} for
// staging/aggregation; lane = (m = lane>>2, c = lane&3) for the 16x4 distance
// matrix. Bit-order of golden (W16 chained-FMA dot, W16 pairwise c2) preserved
// exactly; only load vectorization + scheduling changed.
__global__ __launch_bounds__(64) void sdgnn_k2(
    const int* __restrict__ comm, const int* __restrict__ neigh,
    float* __restrict__ out, int N) {
  #pragma clang fp contract(off)
  __shared__ __align__(16) float L[(MM + CC) * LDST];
  const int lane = threadIdx.x;
  const int n = blockIdx.x;

  const int cidx = comm[(size_t)n * (CC * SS) + (lane & 31)];
  const int nidx = neigh[(size_t)n * MM + (lane & 15)];

  // stage neighbor h1 rows to LDS
  #pragma unroll
  for (int m = 0; m < MM; ++m) {
    int j = __shfl(nidx, m);
    float2 v = *(const float2*)(out + (size_t)j * OUTW + 2 * lane);
    *(float2*)(L + m * LDST + 2 * lane) = v;
  }
  // init centers = mean of 8 member h1 rows: sequential ascending-s adds
  float2 ctr[CC];
  #pragma unroll
  for (int c = 0; c < CC; ++c) {
    float ax = 0.f, ay = 0.f;
    #pragma unroll
    for (int s = 0; s < SS; ++s) {
      int j = __shfl(cidx, c * SS + s);
      float2 v = *(const float2*)(out + (size_t)j * OUTW + 2 * lane);
      ax = ax + v.x;
      ay = ay + v.y;
    }
    ctr[c].x = ax * 0.125f;
    ctr[c].y = ay * 0.125f;
    *(float2*)(L + (MM + c) * LDST + 2 * lane) = ctr[c];
  }
  __syncthreads();

  const int mm = lane >> 2, cc = lane & 3;
  const float4* nrow4 = (const float4*)(L + mm * LDST);
  const float4* crow4 = (const float4*)(L + (MM + cc) * LDST);

  // E-step (golden bit-order, vectorized loads):
  //   c2[L=4j+comp] = ((q0+q1)+(q2+q3))+((q4+q5)+(q6+q7)), q_k = a[16k+L]^2
  //   dot S[L]: chained FMA over ascending k; both reduced by halves-tree
  //   (strides 8,4,2,1). d = c2 - 2*dot; argmin, first-min tie-break.
  auto assign_lbl = [&]() -> int {
    #pragma clang fp contract(off)
    float S2[16];
    #pragma unroll
    for (int j = 0; j < 4; ++j) {
      float4 k0 = crow4[0*4+j], k1 = crow4[1*4+j], k2 = crow4[2*4+j], k3 = crow4[3*4+j];
      float4 k4 = crow4[4*4+j], k5 = crow4[5*4+j], k6 = crow4[6*4+j], k7 = crow4[7*4+j];
      S2[4*j+0] = ((k0.x*k0.x + k1.x*k1.x) + (k2.x*k2.x + k3.x*k3.x))
                + ((k4.x*k4.x + k5.x*k5.x) + (k6.x*k6.x + k7.x*k7.x));
      S2[4*j+1] = ((k0.y*k0.y + k1.y*k1.y) + (k2.y*k2.y + k3.y*k3.y))
                + ((k4.y*k4.y + k5.y*k5.y) + (k6.y*k6.y + k7.y*k7.y));
      S2[4*j+2] = ((k0.z*k0.z + k1.z*k1.z) + (k2.z*k2.z + k3.z*k3.z))
                + ((k4.z*k4.z + k5.z*k5.z) + (k6.z*k6.z + k7.z*k7.z));
      S2[4*j+3] = ((k0.w*k0.w + k1.w*k1.w) + (k2.w*k2.w + k3.w*k3.w))
                + ((k4.w*k4.w + k5.w*k5.w) + (k6.w*k6.w + k7.w*k7.w));
    }
    float cA0 = S2[0] + S2[8],  cA1 = S2[1] + S2[9],  cA2 = S2[2] + S2[10], cA3 = S2[3] + S2[11];
    float cA4 = S2[4] + S2[12], cA5 = S2[5] + S2[13], cA6 = S2[6] + S2[14], cA7 = S2[7] + S2[15];
    float cB0 = cA0 + cA4, cB1 = cA1 + cA5, cB2 = cA2 + cA6, cB3 = cA3 + cA7;
    float cC0 = cB0 + cB2, cC1 = cB1 + cB3;
    float c2 = cC0 + cC1;

    float S[16];
    #pragma unroll
    for (int j = 0; j < 4; ++j) {
      float sx = 0.f, sy = 0.f, sz = 0.f, sw = 0.f;
      #pragma unroll
      for (int k = 0; k < 8; ++k) {
        float4 a = nrow4[k*4+j], b = crow4[k*4+j];
        sx = fmaf(a.x, b.x, sx);
        sy = fmaf(a.y, b.y, sy);
        sz = fmaf(a.z, b.z, sz);
        sw = fmaf(a.w, b.w, sw);
      }
      S[4*j+0] = sx; S[4*j+1] = sy; S[4*j+2] = sz; S[4*j+3] = sw;
    }
    float A0 = S[0] + S[8],  A1 = S[1] + S[9],  A2 = S[2] + S[10], A3 = S[3] + S[11];
    float A4 = S[4] + S[12], A5 = S[5] + S[13], A6 = S[6] + S[14], A7 = S[7] + S[15];
    float B0 = A0 + A4, B1 = A1 + A5, B2 = A2 + A6, B3 = A3 + A7;
    float C0 = B0 + B2, C1 = B1 + B3;
    float dot = C0 + C1;

    float bd = c2 - 2.f * dot;   // 2*dot exact; one rounded subtract
    int bc = cc;
    #pragma unroll
    for (int off = 1; off <= 2; off <<= 1) {
      float od = __shfl_xor(bd, off);
      int oc = __shfl_xor(bc, off);
      if (od < bd || (od == bd && oc < bc)) { bd = od; bc = oc; }
    }
    return bc;  // label of neighbor mm on all 4 group lanes
  };

  // scatter-sum by label + counts, ascending m; one-hot products exact ->
  // fmaf == mul+add bitwise (order-robust).
  auto aggregate = [&](int bc, float2 acc[CC], float cnt[CC]) {
    #pragma clang fp contract(off)
    #pragma unroll
    for (int c = 0; c < CC; ++c) { acc[c].x = 0.f; acc[c].y = 0.f; cnt[c] = 0.f; }
    #pragma unroll
    for (int m = 0; m < MM; ++m) {
      int lbl = __shfl(bc, m * 4);
      float2 v = *(const float2*)(L + m * LDST + 2 * lane);
      #pragma unroll
      for (int c = 0; c < CC; ++c) {
        float sel = (lbl == c) ? 1.f : 0.f;
        acc[c].x = fmaf(sel, v.x, acc[c].x);
        acc[c].y = fmaf(sel, v.y, acc[c].y);
        cnt[c] = cnt[c] + sel;
      }
    }
  };

  // E-step on init centers, then M-step
  int lbl0 = assign_lbl();
  float2 a0[CC]; float c0[CC];
  aggregate(lbl0, a0, c0);
  float2 ctr1[CC];
  #pragma unroll
  for (int c = 0; c < CC; ++c) {
    float den = fmaxf(c0[c], 1.f);       // maximum(cnt,1.0)
    float mx = a0[c].x / den;            // IEEE f32 divide
    float my = a0[c].y / den;
    ctr1[c].x = (c0[c] > 0.f) ? mx : ctr[c].x;  // where(cnt>0, mean, center)
    ctr1[c].y = (c0[c] > 0.f) ? my : ctr[c].y;
  }
  __syncthreads();  // WAR: all reads of old centers done (1 wave: cheap)
  #pragma unroll
  for (int c = 0; c < CC; ++c)
    *(float2*)(L + (MM + c) * LDST + 2 * lane) = ctr1[c];
  __syncthreads();

  // final E-step + scatter-mean (empty -> 0) + maxpool + relu
  int lbl1 = assign_lbl();
  float2 a1[CC]; float c1n[CC];
  aggregate(lbl1, a1, c1n);
  float rx = 0.f, ry = 0.f;
  #pragma unroll
  for (int c = 0; c < CC; ++c) {
    float den = fmaxf(c1n[c], 1.f);
    float gx = a1[c].x / den;            // empty: 0/1 = +0
    float gy = a1[c].y / den;
    rx = (c == 0) ? gx : fmaxf(rx, gx);  // max over c, ascending
    ry = (c == 0) ? gy : fmaxf(ry, gy);
  }
  size_t base = (size_t)n * OUTW + 256 + 2 * lane;
  float2 res;
  res.x = fmaxf(rx, 0.f);
  res.y = fmaxf(ry, 0.f);
  *(float2*)(out + base) = res;
}

extern "C" void kernel_launch(void* const* d_in, const int* in_sizes, int n_in,
                              void* d_out, int out_size, void* d_ws, size_t ws_size,
                              hipStream_t stream) {
  const float* feat = (const float*)d_in[0];
  const int* comm = (const int*)d_in[1];
  const int* neigh = (const int*)d_in[2];
  float* out = (float*)d_out;
  const int N = in_sizes[0] / DD;

  int blocks1 = (N + 3) / 4;   // 4 waves/block, 1 wave per node
  sdgnn_k1<<<blocks1, 256, 0, stream>>>(feat, comm, out, N);
  sdgnn_k2<<<N, 64, 0, stream>>>(comm, neigh, out, N);  // 1 wave per node
}

// Round 14
// 442.099 us; speedup vs baseline: 1.1568x; 1.0207x over previous
//
#include <hip/hip_runtime.h>

#define DD 64      // input feature dim
#define D2 128     // h1 dim
#define CC 4       // communities / clusters
#define SS 8       // members per community
#define MM 16      // neighbors
#define OUTW 384   // output row width (h1 | h1 | cluster)
#define LDST 132   // padded LDS row stride in floats (16B-aligned float4 reads)

// ---------------- Layer 1: h1 = relu([x, max_c mean_s feat[comm]]) ----------
__global__ __launch_bounds__(256) void sdgnn_k1(
    const float* __restrict__ feat, const int* __restrict__ comm,
    float* __restrict__ out, int N) {
  #pragma clang fp contract(off)
  int wid = (int)((blockIdx.x * blockDim.x + threadIdx.x) >> 6);
  int lane = threadIdx.x & 63;
  if (wid >= N) return;
  const int n = wid;
  int cidx = comm[(size_t)n * (CC * SS) + (lane & 31)];
  float x = feat[(size_t)n * DD + lane];
  float g = 0.f;
  #pragma unroll
  for (int c = 0; c < CC; ++c) {
    float a = 0.f;
    #pragma unroll
    for (int s = 0; s < SS; ++s) {
      int j = __shfl(cidx, c * SS + s);
      a = a + feat[(size_t)j * DD + lane];   // sequential, ascending s
    }
    a = a * 0.125f;                          // /8 exact
    g = (c == 0) ? a : fmaxf(g, a);          // max over c, ascending
  }
  float h1a = fmaxf(x, 0.f);
  float h1b = fmaxf(g, 0.f);
  size_t base = (size_t)n * OUTW;
  out[base + lane] = h1a;
  out[base + 64 + lane] = h1b;
  out[base + 128 + lane] = h1a;              // h2 first half == h1 (relu(h1)=h1)
  out[base + 192 + lane] = h1b;
}

// ---------------- Layer 2: 1-step KMeans + scatter-mean + maxpool -----------
// one wave per block. Golden bit-order (W16 chained-FMA dot + W16 pairwise c2,
// halves-tree reduces) preserved exactly; c2 is computed ONCE per wave
// (lane c=lane>>4 computes S[lane&15]; shfl_xor tree == halves-tree bitwise by
// IEEE add commutativity), cnt via ballot+popc (exact small ints).
__global__ __launch_bounds__(64) void sdgnn_k2(
    const int* __restrict__ comm, const int* __restrict__ neigh,
    float* __restrict__ out, int N) {
  #pragma clang fp contract(off)
  __shared__ __align__(16) float L[(MM + CC) * LDST];
  const int lane = threadIdx.x;
  const int n = blockIdx.x;

  const int cidx = comm[(size_t)n * (CC * SS) + (lane & 31)];
  const int nidx = neigh[(size_t)n * MM + (lane & 15)];

  // stage neighbor h1 rows to LDS
  #pragma unroll
  for (int m = 0; m < MM; ++m) {
    int j = __shfl(nidx, m);
    float2 v = *(const float2*)(out + (size_t)j * OUTW + 2 * lane);
    *(float2*)(L + m * LDST + 2 * lane) = v;
  }
  // init centers = mean of 8 member h1 rows: sequential ascending-s adds
  float2 ctr[CC];
  #pragma unroll
  for (int c = 0; c < CC; ++c) {
    float ax = 0.f, ay = 0.f;
    #pragma unroll
    for (int s = 0; s < SS; ++s) {
      int j = __shfl(cidx, c * SS + s);
      float2 v = *(const float2*)(out + (size_t)j * OUTW + 2 * lane);
      ax = ax + v.x;
      ay = ay + v.y;
    }
    ctr[c].x = ax * 0.125f;
    ctr[c].y = ay * 0.125f;
    *(float2*)(L + (MM + c) * LDST + 2 * lane) = ctr[c];
  }
  __syncthreads();

  const int mm = lane >> 2, cc = lane & 3;
  const float4* nrow4 = (const float4*)(L + mm * LDST);
  const float4* crow4 = (const float4*)(L + (MM + cc) * LDST);
  const float* c2row = L + (MM + (lane >> 4)) * LDST;  // c2-compute row (c = lane>>4)
  const int Lc = lane & 15;

  // c2 = np.sum(ctr*ctr,-1), W16 pairwise, computed cooperatively:
  // lane (c,L) computes S[L] = ((q0+q1)+(q2+q3))+((q4+q5)+(q6+q7)); the
  // shfl_xor strides 8,4,2,1 equal the halves-tree bitwise (add commutes).
  auto compute_c2 = [&]() -> float {
    #pragma clang fp contract(off)
    float a0 = c2row[0*16+Lc], a1 = c2row[1*16+Lc], a2 = c2row[2*16+Lc], a3 = c2row[3*16+Lc];
    float a4 = c2row[4*16+Lc], a5 = c2row[5*16+Lc], a6 = c2row[6*16+Lc], a7 = c2row[7*16+Lc];
    float s = ((a0*a0 + a1*a1) + (a2*a2 + a3*a3)) + ((a4*a4 + a5*a5) + (a6*a6 + a7*a7));
    s = s + __shfl_xor(s, 8);
    s = s + __shfl_xor(s, 4);
    s = s + __shfl_xor(s, 2);
    s = s + __shfl_xor(s, 1);
    return __shfl(s, cc << 4);   // c2 of this lane's cluster cc
  };

  // dot: W16 chained-FMA per model-lane, ascending k, halves-tree reduce.
  auto assign_lbl = [&]() -> int {
    #pragma clang fp contract(off)
    float c2 = compute_c2();
    float S[16];
    #pragma unroll
    for (int j = 0; j < 4; ++j) {
      float sx = 0.f, sy = 0.f, sz = 0.f, sw = 0.f;
      #pragma unroll
      for (int k = 0; k < 8; ++k) {
        float4 a = nrow4[k*4+j], b = crow4[k*4+j];
        sx = fmaf(a.x, b.x, sx);
        sy = fmaf(a.y, b.y, sy);
        sz = fmaf(a.z, b.z, sz);
        sw = fmaf(a.w, b.w, sw);
      }
      S[4*j+0] = sx; S[4*j+1] = sy; S[4*j+2] = sz; S[4*j+3] = sw;
    }
    float A0 = S[0] + S[8],  A1 = S[1] + S[9],  A2 = S[2] + S[10], A3 = S[3] + S[11];
    float A4 = S[4] + S[12], A5 = S[5] + S[13], A6 = S[6] + S[14], A7 = S[7] + S[15];
    float B0 = A0 + A4, B1 = A1 + A5, B2 = A2 + A6, B3 = A3 + A7;
    float C0 = B0 + B2, C1 = B1 + B3;
    float dot = C0 + C1;

    float bd = c2 - 2.f * dot;   // 2*dot exact; one rounded subtract
    int bc = cc;
    #pragma unroll
    for (int off = 1; off <= 2; off <<= 1) {
      float od = __shfl_xor(bd, off);
      int oc = __shfl_xor(bc, off);
      if (od < bd || (od == bd && oc < bc)) { bd = od; bc = oc; }
    }
    return bc;  // label of neighbor mm on all 4 group lanes
  };

  // scatter-sum by label (ascending m, fmaf == mul+add bitwise for exact
  // one-hot products); cnt via ballot+popc (exact small ints, order-free).
  auto aggregate = [&](int bc, float2 acc[CC], float cnt[CC]) {
    #pragma clang fp contract(off)
    #pragma unroll
    for (int c = 0; c < CC; ++c) {
      acc[c].x = 0.f; acc[c].y = 0.f;
      unsigned long long mb = __ballot(bc == c);
      cnt[c] = (float)__popcll(mb & 0x1111111111111111ULL);  // lanes 4m
    }
    #pragma unroll
    for (int m = 0; m < MM; ++m) {
      int lbl = __shfl(bc, m * 4);
      float2 v = *(const float2*)(L + m * LDST + 2 * lane);
      #pragma unroll
      for (int c = 0; c < CC; ++c) {
        float sel = (lbl == c) ? 1.f : 0.f;
        acc[c].x = fmaf(sel, v.x, acc[c].x);
        acc[c].y = fmaf(sel, v.y, acc[c].y);
      }
    }
  };

  // E-step on init centers, then M-step
  int lbl0 = assign_lbl();
  float2 a0[CC]; float c0[CC];
  aggregate(lbl0, a0, c0);
  float2 ctr1[CC];
  #pragma unroll
  for (int c = 0; c < CC; ++c) {
    float den = fmaxf(c0[c], 1.f);       // maximum(cnt,1.0)
    float mx = a0[c].x / den;            // IEEE f32 divide
    float my = a0[c].y / den;
    ctr1[c].x = (c0[c] > 0.f) ? mx : ctr[c].x;  // where(cnt>0, mean, center)
    ctr1[c].y = (c0[c] > 0.f) ? my : ctr[c].y;
  }
  __syncthreads();  // WAR: all reads of old centers done (1 wave: cheap)
  #pragma unroll
  for (int c = 0; c < CC; ++c)
    *(float2*)(L + (MM + c) * LDST + 2 * lane) = ctr1[c];
  __syncthreads();

  // final E-step + scatter-mean (empty -> 0) + maxpool + relu
  int lbl1 = assign_lbl();
  float2 a1[CC]; float c1n[CC];
  aggregate(lbl1, a1, c1n);
  float rx = 0.f, ry = 0.f;
  #pragma unroll
  for (int c = 0; c < CC; ++c) {
    float den = fmaxf(c1n[c], 1.f);
    float gx = a1[c].x / den;            // empty: 0/1 = +0
    float gy = a1[c].y / den;
    rx = (c == 0) ? gx : fmaxf(rx, gx);  // max over c, ascending
    ry = (c == 0) ? gy : fmaxf(ry, gy);
  }
  size_t base = (size_t)n * OUTW + 256 + 2 * lane;
  float2 res;
  res.x = fmaxf(rx, 0.f);
  res.y = fmaxf(ry, 0.f);
  *(float2*)(out + base) = res;
}

extern "C" void kernel_launch(void* const* d_in, const int* in_sizes, int n_in,
                              void* d_out, int out_size, void* d_ws, size_t ws_size,
                              hipStream_t stream) {
  const float* feat = (const float*)d_in[0];
  const int* comm = (const int*)d_in[1];
  const int* neigh = (const int*)d_in[2];
  float* out = (float*)d_out;
  const int N = in_sizes[0] / DD;

  int blocks1 = (N + 3) / 4;   // 4 waves/block, 1 wave per node
  sdgnn_k1<<<blocks1, 256, 0, stream>>>(feat, comm, out, N);
  sdgnn_k2<<<N, 64, 0, stream>>>(comm, neigh, out, N);  // 1 wave per node
}